// Round 5
// baseline (569.097 us; speedup 1.0000x reference)
//
#include <hip/hip_runtime.h>
#include <hip/hip_bf16.h>

#define S_LEN 2048
#define D_HEAD 128
#define N_HEAD 32            // B*H = 2*16
#define QBLK 64
#define KBLK 64
#define NKT (S_LEN / KBLK)   // 32
#define KFRAG_THREADS (N_HEAD * NKT * 16 * 64)          // 1,048,576
#define HEAD_FRAG_BYTES (NKT * 16 * 64 * 16)            // 524,288
#define KF_BYTES ((size_t)N_HEAD * HEAD_FRAG_BYTES)     // 16.78 MB
#define WS_NEED (2ull * KF_BYTES)                        // 33.55 MB

typedef short short8 __attribute__((ext_vector_type(8)));
typedef float floatx4 __attribute__((ext_vector_type(4)));

__device__ __forceinline__ unsigned short f2bf(float x) {
  __hip_bfloat16 h = __float2bfloat16(x);   // RNE, HW cvt
  return *reinterpret_cast<unsigned short*>(&h);
}
__device__ __forceinline__ unsigned int pk2(float lo, float hi) {
  return (unsigned int)f2bf(lo) | ((unsigned int)f2bf(hi) << 16);
}

// ======================= fragment-major pre-conversion =======================
// Kf frag (head,kt,nt,ks), lane l=(g*16+c): elements e=0..7 =
//     K[head][kt*64 + nt*16 + c][ks*32 + g*8 + e] * scale
// Vf frag (head,kt,ks,dt), lane l: elements e=0..7 =
//     V[head][kt*64 + ks*32 + g*8 + e][dt*16 + c]
// Stored at frag_base + lane*16 (16B per lane) -> MFMA operand = one
// fully-coalesced global_load_dwordx4.
__global__ __launch_bounds__(256) void preconv(
    const float* __restrict__ K, const float* __restrict__ V,
    unsigned short* __restrict__ Kf, unsigned short* __restrict__ Vf)
{
  const float scale = 0.088388347648318447f;  // 1/sqrt(128)
  int t = blockIdx.x * 256 + threadIdx.x;
  int lane = t & 63;
  int c = lane & 15, g = lane >> 4;
  if (t < KFRAG_THREADS) {
    int fid = t >> 6;
    int ks = fid & 3, nt = (fid >> 2) & 3, kt = (fid >> 4) & 31, head = fid >> 9;
    const float* src = K + ((size_t)head * S_LEN + kt * 64 + nt * 16 + c) * D_HEAD
                         + ks * 32 + g * 8;
    float4 a = *(const float4*)src;
    float4 b = *(const float4*)(src + 4);
    uint4 w;
    w.x = pk2(a.x * scale, a.y * scale);
    w.y = pk2(a.z * scale, a.w * scale);
    w.z = pk2(b.x * scale, b.y * scale);
    w.w = pk2(b.z * scale, b.w * scale);
    *(uint4*)((char*)Kf + (size_t)t * 16) = w;
  } else {
    int u = t - KFRAG_THREADS;
    int fid = u >> 6;
    int dt = fid & 7, ks = (fid >> 3) & 1, kt = (fid >> 4) & 31, head = fid >> 9;
    const float* src = V + ((size_t)head * S_LEN + kt * 64 + ks * 32 + g * 8) * D_HEAD
                         + dt * 16 + c;
    float e0 = src[0 * D_HEAD], e1 = src[1 * D_HEAD];
    float e2 = src[2 * D_HEAD], e3 = src[3 * D_HEAD];
    float e4 = src[4 * D_HEAD], e5 = src[5 * D_HEAD];
    float e6 = src[6 * D_HEAD], e7 = src[7 * D_HEAD];
    uint4 w;
    w.x = pk2(e0, e1);
    w.y = pk2(e2, e3);
    w.z = pk2(e4, e5);
    w.w = pk2(e6, e7);
    *(uint4*)((char*)Vf + (size_t)u * 16) = w;
  }
}

// ======================= main fused attention =======================
// 256 threads = 4 waves, 16 q-rows per wave, QBLK=64 per block.
// No K/V LDS staging, no __syncthreads: MFMA fragments load directly from
// the fragment-major Kf/Vf (L2-resident per XCD). Only wave-private Ps in LDS.
__global__ __launch_bounds__(256, 4) void attn_main(
    const float* __restrict__ Q, const unsigned short* __restrict__ Kf,
    const unsigned short* __restrict__ Vf, float* __restrict__ Out,
    float* __restrict__ Sc)
{
  __shared__ unsigned short Ps[QBLK * 64];   // 8 KB: 64 rows x 128B, swizzled

  const int bid  = blockIdx.x;
  const int slot = bid >> 3;                 // 0..127
  const int head = (bid & 7) * 4 + (slot >> 5);   // same-head blocks -> same XCD
  const int q0   = (slot & 31) * QBLK;

  const float* Qh = Q + (size_t)head * S_LEN * D_HEAD;
  const char* Kfh = (const char*)Kf + (size_t)head * HEAD_FRAG_BYTES;
  const char* Vfh = (const char*)Vf + (size_t)head * HEAD_FRAG_BYTES;
  float* Oh = Out + (size_t)head * S_LEN * D_HEAD;
  float* Sh = Sc  + (size_t)head * S_LEN * S_LEN;

  const int tid  = threadIdx.x;
  const int wid  = tid >> 6;
  const int lane = tid & 63;
  const int c    = lane & 15;
  const int g    = lane >> 4;

  // ---- Q fragments (A operand): row = lane&15, k = 8*(lane>>4)+e ----
  short8 qf[4];
  {
    const float* qrow = Qh + (size_t)(q0 + wid * 16 + c) * D_HEAD + g * 8;
#pragma unroll
    for (int ks = 0; ks < 4; ++ks) {
      float4 a = *(const float4*)(qrow + ks * 32);
      float4 b = *(const float4*)(qrow + ks * 32 + 4);
      unsigned int p0 = pk2(a.x, a.y), p1 = pk2(a.z, a.w);
      unsigned int p2 = pk2(b.x, b.y), p3 = pk2(b.z, b.w);
      short8 f;
      f[0] = (short)(p0 & 0xffff); f[1] = (short)(p0 >> 16);
      f[2] = (short)(p1 & 0xffff); f[3] = (short)(p1 >> 16);
      f[4] = (short)(p2 & 0xffff); f[5] = (short)(p2 >> 16);
      f[6] = (short)(p3 & 0xffff); f[7] = (short)(p3 >> 16);
      qf[ks] = f;
    }
  }

  const float LOG2E = 1.44269504088896341f;

  // ================= PASS 1: row sums of exp =================
  float esum[4] = {0.f, 0.f, 0.f, 0.f};   // rows q = q0 + wid*16 + 4g + j
  for (int kt = 0; kt < NKT; ++kt) {
    const char* kbase = Kfh + (size_t)kt * 16384 + lane * 16;
#pragma unroll
    for (int nt = 0; nt < 4; ++nt) {
      floatx4 acc = {0.f, 0.f, 0.f, 0.f};
#pragma unroll
      for (int ks = 0; ks < 4; ++ks) {
        short8 bf = *(const short8*)(kbase + (nt * 4 + ks) * 1024);
        acc = __builtin_amdgcn_mfma_f32_16x16x32_bf16(qf[ks], bf, acc, 0, 0, 0);
      }
      esum[0] += __builtin_exp2f(acc[0] * LOG2E);
      esum[1] += __builtin_exp2f(acc[1] * LOG2E);
      esum[2] += __builtin_exp2f(acc[2] * LOG2E);
      esum[3] += __builtin_exp2f(acc[3] * LOG2E);
    }
  }

  float l2s[4];
#pragma unroll
  for (int j = 0; j < 4; ++j) {
    float s = esum[j];
    s += __shfl_xor(s, 1, 64);
    s += __shfl_xor(s, 2, 64);
    s += __shfl_xor(s, 4, 64);
    s += __shfl_xor(s, 8, 64);
    l2s[j] = __log2f(s);
  }

  // ================= PASS 2: score write + PV =================
  floatx4 oacc[8];
#pragma unroll
  for (int dt = 0; dt < 8; ++dt)
    oacc[dt] = (floatx4){0.f, 0.f, 0.f, 0.f};

  for (int kt = 0; kt < NKT; ++kt) {
    const char* kbase = Kfh + (size_t)kt * 16384 + lane * 16;
    const char* vbase = Vfh + (size_t)kt * 16384 + lane * 16;

    // QK^T -> p -> score(global f32) + Ps(LDS bf16, wave-private rows)
#pragma unroll
    for (int nt = 0; nt < 4; ++nt) {
      floatx4 acc = {0.f, 0.f, 0.f, 0.f};
#pragma unroll
      for (int ks = 0; ks < 4; ++ks) {
        short8 bf = *(const short8*)(kbase + (nt * 4 + ks) * 1024);
        acc = __builtin_amdgcn_mfma_f32_16x16x32_bf16(qf[ks], bf, acc, 0, 0, 0);
      }
      float* srow = Sh + (size_t)(q0 + wid * 16 + 4 * g) * S_LEN
                       + (size_t)kt * KBLK + nt * 16 + c;
#pragma unroll
      for (int j = 0; j < 4; ++j) {
        float p = __builtin_exp2f(__builtin_fmaf(acc[j], LOG2E, -l2s[j]));
        srow[(size_t)j * S_LEN] = p;
        int q = wid * 16 + 4 * g + j;
        int byte = q * 128 + (((nt * 16 + c) * 2) ^ ((q & 7) << 4));
        *(unsigned short*)((char*)Ps + byte) = f2bf(p);
      }
    }

    // PV: oacc += P @ V  (Ps rows wave-private; same-wave lgkmcnt ordering)
#pragma unroll
    for (int ks = 0; ks < 2; ++ks) {
      int r0 = wid * 16 + c;
      short8 pa = *(const short8*)((char*)Ps + r0 * 128
                      + ((ks * 64 + g * 16) ^ ((r0 & 7) << 4)));
#pragma unroll
      for (int dt = 0; dt < 8; ++dt) {
        short8 vf = *(const short8*)(vbase + (ks * 8 + dt) * 1024);
        oacc[dt] = __builtin_amdgcn_mfma_f32_16x16x32_bf16(pa, vf, oacc[dt], 0, 0, 0);
      }
    }
  }

  // ---- epilogue ----
#pragma unroll
  for (int dt = 0; dt < 8; ++dt)
#pragma unroll
    for (int j = 0; j < 4; ++j)
      Oh[(size_t)(q0 + wid * 16 + 4 * g + j) * D_HEAD + dt * 16 + c] = oacc[dt][j];
}

// ======================= fallback (proven r1 kernel) =======================
__global__ __launch_bounds__(256, 2) void attn_fused(
    const float* __restrict__ Q, const float* __restrict__ K,
    const float* __restrict__ V, float* __restrict__ Out,
    float* __restrict__ Sc)
{
  __shared__ unsigned short Kt[KBLK][136];
  __shared__ unsigned short Vts[D_HEAD][72];
  __shared__ unsigned short Psl[128][72];

  const int bid  = blockIdx.x;
  const int slot = bid >> 3;
  const int head = (bid & 7) * 4 + (slot >> 4);
  const int q0   = (slot & 15) * 128;

  const float* Qh = Q + (size_t)head * S_LEN * D_HEAD;
  const float* Kh = K + (size_t)head * S_LEN * D_HEAD;
  const float* Vh = V + (size_t)head * S_LEN * D_HEAD;
  float* Oh = Out + (size_t)head * S_LEN * D_HEAD;
  float* Sh = Sc  + (size_t)head * S_LEN * S_LEN;

  const int tid  = threadIdx.x;
  const int wid  = tid >> 6;
  const int lane = tid & 63;
  const int c    = lane & 15;
  const int g    = lane >> 4;
  const float scale = 0.088388347648318447f;

  short8 qf[2][4];
#pragma unroll
  for (int mt = 0; mt < 2; ++mt) {
    const float* qrow = Qh + (size_t)(q0 + wid * 32 + mt * 16 + c) * D_HEAD + g * 8;
#pragma unroll
    for (int ks = 0; ks < 4; ++ks) {
      float4 a = *(const float4*)(qrow + ks * 32);
      float4 b = *(const float4*)(qrow + ks * 32 + 4);
      short8 f;
      f[0] = (short)f2bf(a.x); f[1] = (short)f2bf(a.y);
      f[2] = (short)f2bf(a.z); f[3] = (short)f2bf(a.w);
      f[4] = (short)f2bf(b.x); f[5] = (short)f2bf(b.y);
      f[6] = (short)f2bf(b.z); f[7] = (short)f2bf(b.w);
      qf[mt][ks] = f;
    }
  }

  auto stageK = [&](int kt) {
    const float* src = Kh + (size_t)kt * KBLK * D_HEAD;
#pragma unroll
    for (int i = 0; i < 8; ++i) {
      int id = i * 256 + tid;
      int r = id >> 5, c4 = id & 31;
      float4 v = *(const float4*)(src + r * D_HEAD + c4 * 4);
      uint2 w;
      w.x = pk2(v.x * scale, v.y * scale);
      w.y = pk2(v.z * scale, v.w * scale);
      *(uint2*)&Kt[r][c4 * 4] = w;
    }
  };
  auto stageV = [&](int kt) {
    const float* src = Vh + (size_t)kt * KBLK * D_HEAD;
#pragma unroll
    for (int i = 0; i < 4; ++i) {
      int c4 = (tid & 7) | (i << 3);
      int r = (tid >> 3) * 2;
      const float* p0 = src + (size_t)r * D_HEAD + c4 * 4;
      float4 a = *(const float4*)p0;
      float4 b = *(const float4*)(p0 + D_HEAD);
      *(unsigned int*)&Vts[c4 * 4 + 0][r] = pk2(a.x, b.x);
      *(unsigned int*)&Vts[c4 * 4 + 1][r] = pk2(a.y, b.y);
      *(unsigned int*)&Vts[c4 * 4 + 2][r] = pk2(a.z, b.z);
      *(unsigned int*)&Vts[c4 * 4 + 3][r] = pk2(a.w, b.w);
    }
  };

  float esum[2][4] = {};
  for (int kt = 0; kt < NKT; ++kt) {
    stageK(kt);
    __syncthreads();
#pragma unroll
    for (int nt = 0; nt < 4; ++nt) {
      short8 bf[4];
#pragma unroll
      for (int ks = 0; ks < 4; ++ks)
        bf[ks] = *(const short8*)&Kt[nt * 16 + c][ks * 32 + g * 8];
#pragma unroll
      for (int mt = 0; mt < 2; ++mt) {
        floatx4 acc = {0.f, 0.f, 0.f, 0.f};
#pragma unroll
        for (int ks = 0; ks < 4; ++ks)
          acc = __builtin_amdgcn_mfma_f32_16x16x32_bf16(qf[mt][ks], bf[ks], acc, 0, 0, 0);
        esum[mt][0] += __expf(acc[0]);
        esum[mt][1] += __expf(acc[1]);
        esum[mt][2] += __expf(acc[2]);
        esum[mt][3] += __expf(acc[3]);
      }
    }
    __syncthreads();
  }

  float rinv[2][4];
#pragma unroll
  for (int mt = 0; mt < 2; ++mt)
#pragma unroll
    for (int j = 0; j < 4; ++j) {
      float s = esum[mt][j];
      s += __shfl_xor(s, 1, 64);
      s += __shfl_xor(s, 2, 64);
      s += __shfl_xor(s, 4, 64);
      s += __shfl_xor(s, 8, 64);
      rinv[mt][j] = 1.0f / s;
    }

  floatx4 oacc[2][8];
#pragma unroll
  for (int mt = 0; mt < 2; ++mt)
#pragma unroll
    for (int dt = 0; dt < 8; ++dt)
      oacc[mt][dt] = (floatx4){0.f, 0.f, 0.f, 0.f};

  for (int kt = 0; kt < NKT; ++kt) {
    stageK(kt);
    stageV(kt);
    __syncthreads();
#pragma unroll
    for (int nt = 0; nt < 4; ++nt) {
      short8 bf[4];
#pragma unroll
      for (int ks = 0; ks < 4; ++ks)
        bf[ks] = *(const short8*)&Kt[nt * 16 + c][ks * 32 + g * 8];
#pragma unroll
      for (int mt = 0; mt < 2; ++mt) {
        floatx4 acc = {0.f, 0.f, 0.f, 0.f};
#pragma unroll
        for (int ks = 0; ks < 4; ++ks)
          acc = __builtin_amdgcn_mfma_f32_16x16x32_bf16(qf[mt][ks], bf[ks], acc, 0, 0, 0);
        float* srow = Sh + (size_t)(q0 + wid * 32 + mt * 16 + 4 * g) * S_LEN
                         + (size_t)kt * KBLK + nt * 16 + c;
#pragma unroll
        for (int j = 0; j < 4; ++j) {
          float p = __expf(acc[j]) * rinv[mt][j];
          srow[(size_t)j * S_LEN] = p;
          Psl[wid * 32 + mt * 16 + 4 * g + j][nt * 16 + c] = f2bf(p);
        }
      }
    }
#pragma unroll
    for (int ks = 0; ks < 2; ++ks) {
      short8 pa0 = *(const short8*)&Psl[wid * 32 + c][ks * 32 + g * 8];
      short8 pa1 = *(const short8*)&Psl[wid * 32 + 16 + c][ks * 32 + g * 8];
#pragma unroll
      for (int dt = 0; dt < 8; ++dt) {
        short8 vf = *(const short8*)&Vts[dt * 16 + c][ks * 32 + g * 8];
        oacc[0][dt] = __builtin_amdgcn_mfma_f32_16x16x32_bf16(pa0, vf, oacc[0][dt], 0, 0, 0);
        oacc[1][dt] = __builtin_amdgcn_mfma_f32_16x16x32_bf16(pa1, vf, oacc[1][dt], 0, 0, 0);
      }
    }
    __syncthreads();
  }

#pragma unroll
  for (int mt = 0; mt < 2; ++mt)
#pragma unroll
    for (int dt = 0; dt < 8; ++dt)
#pragma unroll
      for (int j = 0; j < 4; ++j)
        Oh[(size_t)(q0 + wid * 32 + mt * 16 + 4 * g + j) * D_HEAD + dt * 16 + c] =
            oacc[mt][dt][j];
}

extern "C" void kernel_launch(void* const* d_in, const int* in_sizes, int n_in,
                              void* d_out, int out_size, void* d_ws, size_t ws_size,
                              hipStream_t stream) {
  (void)in_sizes; (void)n_in; (void)out_size;
  const float* Q = (const float*)d_in[0];
  const float* K = (const float*)d_in[1];
  const float* V = (const float*)d_in[2];
  float* Out = (float*)d_out;
  float* Sc  = Out + (size_t)N_HEAD * S_LEN * D_HEAD;

  if (ws_size >= WS_NEED) {
    unsigned short* Kfrag = (unsigned short*)d_ws;
    unsigned short* Vfrag = (unsigned short*)((char*)d_ws + KF_BYTES);
    preconv<<<(2 * KFRAG_THREADS) / 256, 256, 0, stream>>>(K, V, Kfrag, Vfrag);
    attn_main<<<N_HEAD * (S_LEN / QBLK), 256, 0, stream>>>(Q, Kfrag, Vfrag, Out, Sc);
  } else {
    attn_fused<<<N_HEAD * (S_LEN / 128), 256, 0, stream>>>(Q, K, V, Out, Sc);
  }
}